// Round 7
// baseline (116.546 us; speedup 1.0000x reference)
//
#include <hip/hip_runtime.h>

// INP=4096 MSK=64 HID=64 OUT=10  L1=64 L2=256 L3=128  B=16384  WVEC=4810
// k_prep : W1^T -> f16, W2/W3/W4 -> f16
// k_main : per 32 samples (grid 512, 8 waves, 4 waves/SIMD occupancy):
//   xm random-gather issue -> layer1 lane-parallel dedup-sum (f16 W1T) ->
//   layers 2+3 f16 MFMA (swizzled LDS h1/h2/h3) -> W4 GEMM from L2 with
//   per-chunk LDS-sourced B-fragments -> fused per-sample einsum epilogues.
// VGPR budget ~100 (<=128 enforced by __launch_bounds__(512,4)).

typedef _Float16 f16;
typedef _Float16 f16x8 __attribute__((ext_vector_type(8)));
typedef _Float16 f16x4 __attribute__((ext_vector_type(4)));
typedef float    f32x4 __attribute__((ext_vector_type(4)));

#define NPAD 4864   // 4810 W4 rows padded to 76*64

// ---------------------------------------------------------------- prep
__global__ __launch_bounds__(256) void k_prep(
    const float* __restrict__ W1, const float* __restrict__ W2,
    const float* __restrict__ W3, const float* __restrict__ W4,
    f16* __restrict__ W1Th, f16* __restrict__ W2h,
    f16* __restrict__ W3h, f16* __restrict__ W4h)
{
    const int tid = blockIdx.x * 256 + threadIdx.x;
    const int stride = gridDim.x * 256;
    for (int e = tid; e < 4096 * 64; e += stride) {
        int j = e >> 6, i = e & 63;
        W1Th[e] = (f16)W1[(size_t)i * 4096 + j];
    }
    for (int e = tid; e < NPAD * 128; e += stride) {
        int n = e >> 7;
        W4h[e] = (n < 4810) ? (f16)W4[e] : (f16)0.f;
    }
    for (int e = tid; e < 256 * 64; e += stride)  W2h[e] = (f16)W2[e];
    for (int e = tid; e < 128 * 256; e += stride) W3h[e] = (f16)W3[e];
}

// ---------------------------------------------------------------- main
// LDS (28.7 KB):
//  uA (20480B): phase A = h2[32][256]f16 swz (16384) + h1[32][64]f16 swz (@16384)
//               phase B = xm[32][68]f32 (@0) + hid[32][68]f32 (@8704)
//                         + res[32][12]f32 (@17408)
//  uB (8192B) : idx[32][64]i32  ->  h3[32][128]f16 swz
__global__ __launch_bounds__(512, 4) void k_main(
    const float* __restrict__ data, const int* __restrict__ midx,
    const f16* __restrict__ W1Th, const float* __restrict__ b1,
    const f16* __restrict__ W2h, const float* __restrict__ b2,
    const f16* __restrict__ W3h, const float* __restrict__ b3,
    const f16* __restrict__ W4h, const float* __restrict__ b4,
    float* __restrict__ out)
{
    __shared__ __align__(16) char uA[20480];
    __shared__ __align__(16) char uB[8192];

    const int t = threadIdx.x, w = t >> 6, lane = t & 63;
    const int lr = lane & 15, g = lane >> 4;
    const int cw = w;                      // chunk group 0..7
    const int row0 = blockIdx.x * 32;
    const f32x4 zero = {0.f, 0.f, 0.f, 0.f};

    int*  idx_s = (int*)uB;
    char* h2b   = uA;
    char* h1b   = uA + 16384;
    char* h3b   = uB;
    float* xm_s  = (float*)uA;             // [32][68]
    float* hid_s = (float*)(uA + 8704);    // [32][68]
    float* res_s = (float*)(uA + 17408);   // [32][12]

    // ---- phase 1: mask indices -> LDS
    for (int e = t; e < 2048; e += 512)
        idx_s[e] = midx[(size_t)row0 * 64 + e];
    __syncthreads();

    // ---- phase 2: issue xm random gather (4 loads/thread)
    float xr[4];
    #pragma unroll
    for (int k = 0; k < 4; ++k) {
        const int e = k * 512 + t;           // e = s*64 + m
        xr[k] = data[(size_t)(row0 + (e >> 6)) * 4096 + idx_s[e]];
    }

    // ---- phase 3: layer 1 dedup gather-sum (wave w: samples 4w..4w+3)
    // lane (g = idx-quarter, lr = hidden-slice); shuffle-reduce over g.
    {
        const f32x4 b1v = *(const f32x4*)&b1[lr * 4];
        #pragma unroll
        for (int p = 0; p < 2; ++p) {
            const int s0 = 4 * w + 2 * p, s1 = s0 + 1;
            f32x4 a0 = zero, a1 = zero;
            #pragma unroll
            for (int tt = 0; tt < 16; ++tt) {
                const int i = g * 16 + tt;
                const int c0 = idx_s[s0 * 64 + i];
                const int q0 = (i > 0) ? idx_s[s0 * 64 + i - 1] : -1;
                const int c1 = idx_s[s1 * 64 + i];
                const int q1 = (i > 0) ? idx_s[s1 * 64 + i - 1] : -1;
                const f16x4 w0 = *(const f16x4*)&W1Th[c0 * 64 + lr * 4];
                const f16x4 w1 = *(const f16x4*)&W1Th[c1 * 64 + lr * 4];
                #pragma unroll
                for (int q = 0; q < 4; ++q) {
                    a0[q] += (c0 != q0) ? (float)w0[q] : 0.f;
                    a1[q] += (c1 != q1) ? (float)w1[q] : 0.f;
                }
            }
            #pragma unroll
            for (int q = 0; q < 4; ++q) {
                a0[q] += __shfl_xor(a0[q], 16);
                a0[q] += __shfl_xor(a0[q], 32);
                a1[q] += __shfl_xor(a1[q], 16);
                a1[q] += __shfl_xor(a1[q], 32);
            }
            if (g == 0) {
                f16x4 h0, h1v;
                #pragma unroll
                for (int q = 0; q < 4; ++q) {
                    h0[q]  = (f16)fmaxf(a0[q] + b1v[q], 0.f);
                    h1v[q] = (f16)fmaxf(a1[q] + b1v[q], 0.f);
                }
                *(f16x4*)(h1b + ((s0 * 128 + lr * 8) ^ ((s0 & 7) << 4))) = h0;
                *(f16x4*)(h1b + ((s1 * 128 + lr * 8) ^ ((s1 & 7) << 4))) = h1v;
            }
        }
    }
    __syncthreads();

    // ---- phase 4: layer 2 (wave w owns n in [32w,32w+32), K=64)
    {
        f16x8 a2[2][2], bh[2][2];
        #pragma unroll
        for (int mt = 0; mt < 2; ++mt)
            #pragma unroll
            for (int kk = 0; kk < 2; ++kk)
                a2[mt][kk] = *(const f16x8*)&W2h[(32 * w + 16 * mt + lr) * 64 + 32 * kk + 8 * g];
        #pragma unroll
        for (int rt = 0; rt < 2; ++rt)
            #pragma unroll
            for (int kk = 0; kk < 2; ++kk) {
                const int s = 16 * rt + lr;
                bh[rt][kk] = *(const f16x8*)(h1b + ((s * 128 + (32 * kk + 8 * g) * 2) ^ ((s & 7) << 4)));
            }

        f32x4 acc2[2][2];
        #pragma unroll
        for (int mt = 0; mt < 2; ++mt)
            #pragma unroll
            for (int rt = 0; rt < 2; ++rt) {
                acc2[mt][rt] = __builtin_amdgcn_mfma_f32_16x16x32_f16(a2[mt][0], bh[rt][0], zero, 0, 0, 0);
                acc2[mt][rt] = __builtin_amdgcn_mfma_f32_16x16x32_f16(a2[mt][1], bh[rt][1], acc2[mt][rt], 0, 0, 0);
            }

        #pragma unroll
        for (int mt = 0; mt < 2; ++mt) {
            const f32x4 bv = *(const f32x4*)&b2[32 * w + 16 * mt + 4 * g];
            #pragma unroll
            for (int rt = 0; rt < 2; ++rt) {
                const int s = 16 * rt + lr;
                f16x4 hv;
                #pragma unroll
                for (int q = 0; q < 4; ++q)
                    hv[q] = (f16)fmaxf(acc2[mt][rt][q] + bv[q], 0.f);
                *(f16x4*)(h2b + ((s * 512 + (32 * w + 16 * mt + 4 * g) * 2) ^ ((s & 7) << 4))) = hv;
            }
        }
    }
    __syncthreads();

    // ---- phase 5: layer 3 (wave w owns n in [16w,16w+16), K=256)
    {
        f32x4 acc3[2] = {zero, zero};
        #pragma unroll 2
        for (int kk = 0; kk < 8; ++kk) {
            const f16x8 a3 = *(const f16x8*)&W3h[(16 * w + lr) * 256 + 32 * kk + 8 * g];
            #pragma unroll
            for (int rt = 0; rt < 2; ++rt) {
                const int s = 16 * rt + lr;
                const f16x8 bb = *(const f16x8*)(h2b + ((s * 512 + (32 * kk + 8 * g) * 2) ^ ((s & 7) << 4)));
                acc3[rt] = __builtin_amdgcn_mfma_f32_16x16x32_f16(a3, bb, acc3[rt], 0, 0, 0);
            }
        }
        const f32x4 bv3 = *(const f32x4*)&b3[16 * w + 4 * g];
        #pragma unroll
        for (int rt = 0; rt < 2; ++rt) {
            const int s = 16 * rt + lr;
            f16x4 hv;
            #pragma unroll
            for (int q = 0; q < 4; ++q)
                hv[q] = (f16)fmaxf(acc3[rt][q] + bv3[q], 0.f);
            *(f16x4*)(h3b + ((s * 256 + (16 * w + 4 * g) * 2) ^ ((s & 7) << 4))) = hv;
        }
    }
    __syncthreads();   // h3 ready; h2/h1/idx dead

    // ---- phase 6: xm regs -> LDS
    #pragma unroll
    for (int k = 0; k < 4; ++k) {
        const int e = k * 512 + t;
        xm_s[(e >> 6) * 68 + (e & 63)] = xr[k];
    }
    __syncthreads();

    // ================= W4 GEMM (A from L2, B from LDS h3) =================
    // Per chunk: rolling A ping-pong (aP/aQ), per-kk B-fragments from LDS.
    // D layout: col = lane&15 (sample within u-set), row = 4g+q (+16mt).

    // ---- inp_w chunks: c = cw + 8j -> hid_s[sample][c]
    for (int j = 0; j < 8; ++j) {
        const int c = cw + 8 * j;
        const f16* Ab = W4h + (size_t)(64 * c) * 128;
        f16x8 aP[4], aQ[4];
        #pragma unroll
        for (int mt = 0; mt < 4; ++mt)
            aP[mt] = *(const f16x8*)&Ab[(16 * mt + lr) * 128 + 8 * g];
        #pragma unroll
        for (int mt = 0; mt < 4; ++mt)
            aQ[mt] = *(const f16x8*)&Ab[(16 * mt + lr) * 128 + 32 + 8 * g];

        f32x4 acc[4][2];
        #pragma unroll
        for (int kk = 0; kk < 4; ++kk) {
            f16x8 bf[2];
            #pragma unroll
            for (int u = 0; u < 2; ++u) {
                const int s = 16 * u + lr;
                bf[u] = *(const f16x8*)(h3b + ((s * 256 + (32 * kk + 8 * g) * 2) ^ ((s & 7) << 4)));
            }
            if (kk == 0) {
                #pragma unroll
                for (int mt = 0; mt < 4; ++mt)
                    #pragma unroll
                    for (int u = 0; u < 2; ++u)
                        acc[mt][u] = __builtin_amdgcn_mfma_f32_16x16x32_f16(aP[mt], bf[u], zero, 0, 0, 0);
                #pragma unroll
                for (int mt = 0; mt < 4; ++mt)      // refill P with kk=2
                    aP[mt] = *(const f16x8*)&Ab[(16 * mt + lr) * 128 + 64 + 8 * g];
            } else if (kk == 1) {
                #pragma unroll
                for (int mt = 0; mt < 4; ++mt)
                    #pragma unroll
                    for (int u = 0; u < 2; ++u)
                        acc[mt][u] = __builtin_amdgcn_mfma_f32_16x16x32_f16(aQ[mt], bf[u], acc[mt][u], 0, 0, 0);
                #pragma unroll
                for (int mt = 0; mt < 4; ++mt)      // refill Q with kk=3
                    aQ[mt] = *(const f16x8*)&Ab[(16 * mt + lr) * 128 + 96 + 8 * g];
            } else if (kk == 2) {
                #pragma unroll
                for (int mt = 0; mt < 4; ++mt)
                    #pragma unroll
                    for (int u = 0; u < 2; ++u)
                        acc[mt][u] = __builtin_amdgcn_mfma_f32_16x16x32_f16(aP[mt], bf[u], acc[mt][u], 0, 0, 0);
            } else {
                #pragma unroll
                for (int mt = 0; mt < 4; ++mt)
                    #pragma unroll
                    for (int u = 0; u < 2; ++u)
                        acc[mt][u] = __builtin_amdgcn_mfma_f32_16x16x32_f16(aQ[mt], bf[u], acc[mt][u], 0, 0, 0);
            }
        }

        f32x4 bv[4];
        #pragma unroll
        for (int mt = 0; mt < 4; ++mt)
            bv[mt] = *(const f32x4*)&b4[64 * c + 16 * mt + 4 * g];

        #pragma unroll
        for (int u = 0; u < 2; ++u) {
            const int s = 16 * u + lr;
            float sum = 0.f;
            #pragma unroll
            for (int mt = 0; mt < 4; ++mt) {
                const f32x4 xv = *(const f32x4*)&xm_s[s * 68 + 16 * mt + 4 * g];
                #pragma unroll
                for (int q = 0; q < 4; ++q)
                    sum += (acc[mt][u][q] + bv[mt][q]) * xv[q];
            }
            sum += __shfl_xor(sum, 16);
            sum += __shfl_xor(sum, 32);
            if (g == 0) hid_s[s * 68 + c] = sum;
        }
    }
    __syncthreads();

    // ---- chunk 64: inp_b (waves cw<4 handle m-tile mt=cw) + ReLU
    if (cw < 4) {
        const f16* Ab = W4h + (size_t)4096 * 128;
        f32x4 accb[2] = {zero, zero};
        #pragma unroll
        for (int kk = 0; kk < 4; ++kk) {
            const f16x8 av = *(const f16x8*)&Ab[(16 * cw + lr) * 128 + 32 * kk + 8 * g];
            #pragma unroll
            for (int u = 0; u < 2; ++u) {
                const int s = 16 * u + lr;
                const f16x8 bf = *(const f16x8*)(h3b + ((s * 256 + (32 * kk + 8 * g) * 2) ^ ((s & 7) << 4)));
                accb[u] = __builtin_amdgcn_mfma_f32_16x16x32_f16(av, bf, accb[u], 0, 0, 0);
            }
        }
        const int hb = 16 * cw + 4 * g;
        const f32x4 bv = *(const f32x4*)&b4[4096 + hb];
        #pragma unroll
        for (int u = 0; u < 2; ++u) {
            const int s = 16 * u + lr;
            f32x4 hv = *(const f32x4*)&hid_s[s * 68 + hb];
            #pragma unroll
            for (int q = 0; q < 4; ++q)
                hv[q] = fmaxf(hv[q] + accb[u][q] + bv[q], 0.f);
            *(f32x4*)&hid_s[s * 68 + hb] = hv;
        }
    }
    __syncthreads();

    // ---- out_w chunks: c in [65,74], (c-65) mod 8 == cw
    for (int c = 65 + cw; c <= 74; c += 8) {
        const f16* Ab = W4h + (size_t)(64 * c) * 128;
        f16x8 aP[4], aQ[4];
        #pragma unroll
        for (int mt = 0; mt < 4; ++mt)
            aP[mt] = *(const f16x8*)&Ab[(16 * mt + lr) * 128 + 8 * g];
        #pragma unroll
        for (int mt = 0; mt < 4; ++mt)
            aQ[mt] = *(const f16x8*)&Ab[(16 * mt + lr) * 128 + 32 + 8 * g];

        f32x4 acc[4][2];
        #pragma unroll
        for (int kk = 0; kk < 4; ++kk) {
            f16x8 bf[2];
            #pragma unroll
            for (int u = 0; u < 2; ++u) {
                const int s = 16 * u + lr;
                bf[u] = *(const f16x8*)(h3b + ((s * 256 + (32 * kk + 8 * g) * 2) ^ ((s & 7) << 4)));
            }
            if (kk == 0) {
                #pragma unroll
                for (int mt = 0; mt < 4; ++mt)
                    #pragma unroll
                    for (int u = 0; u < 2; ++u)
                        acc[mt][u] = __builtin_amdgcn_mfma_f32_16x16x32_f16(aP[mt], bf[u], zero, 0, 0, 0);
                #pragma unroll
                for (int mt = 0; mt < 4; ++mt)
                    aP[mt] = *(const f16x8*)&Ab[(16 * mt + lr) * 128 + 64 + 8 * g];
            } else if (kk == 1) {
                #pragma unroll
                for (int mt = 0; mt < 4; ++mt)
                    #pragma unroll
                    for (int u = 0; u < 2; ++u)
                        acc[mt][u] = __builtin_amdgcn_mfma_f32_16x16x32_f16(aQ[mt], bf[u], acc[mt][u], 0, 0, 0);
                #pragma unroll
                for (int mt = 0; mt < 4; ++mt)
                    aQ[mt] = *(const f16x8*)&Ab[(16 * mt + lr) * 128 + 96 + 8 * g];
            } else if (kk == 2) {
                #pragma unroll
                for (int mt = 0; mt < 4; ++mt)
                    #pragma unroll
                    for (int u = 0; u < 2; ++u)
                        acc[mt][u] = __builtin_amdgcn_mfma_f32_16x16x32_f16(aP[mt], bf[u], acc[mt][u], 0, 0, 0);
            } else {
                #pragma unroll
                for (int mt = 0; mt < 4; ++mt)
                    #pragma unroll
                    for (int u = 0; u < 2; ++u)
                        acc[mt][u] = __builtin_amdgcn_mfma_f32_16x16x32_f16(aQ[mt], bf[u], acc[mt][u], 0, 0, 0);
            }
        }

        f32x4 bv[4];
        #pragma unroll
        for (int mt = 0; mt < 4; ++mt)
            bv[mt] = *(const f32x4*)&b4[64 * c + 16 * mt + 4 * g];

        #pragma unroll
        for (int u = 0; u < 2; ++u) {
            const int s = 16 * u + lr;
            float sum = 0.f;
            #pragma unroll
            for (int mt = 0; mt < 4; ++mt) {
                const f32x4 hv = *(const f32x4*)&hid_s[s * 68 + 16 * mt + 4 * g];
                #pragma unroll
                for (int q = 0; q < 4; ++q)
                    sum += (acc[mt][u][q] + bv[mt][q]) * hv[q];
            }
            sum += __shfl_xor(sum, 16);
            sum += __shfl_xor(sum, 32);
            if (g == 0) res_s[s * 12 + (c - 65)] = sum;
        }
    }
    __syncthreads();

    // ---- chunk 75: out_b (rows 4800..4809)
    if (cw == 7) {
        const f16* Ab = W4h + (size_t)4800 * 128;
        f32x4 accb[2] = {zero, zero};
        #pragma unroll
        for (int kk = 0; kk < 4; ++kk) {
            const f16x8 av = *(const f16x8*)&Ab[lr * 128 + 32 * kk + 8 * g];
            #pragma unroll
            for (int u = 0; u < 2; ++u) {
                const int s = 16 * u + lr;
                const f16x8 bf = *(const f16x8*)(h3b + ((s * 256 + (32 * kk + 8 * g) * 2) ^ ((s & 7) << 4)));
                accb[u] = __builtin_amdgcn_mfma_f32_16x16x32_f16(av, bf, accb[u], 0, 0, 0);
            }
        }
        #pragma unroll
        for (int u = 0; u < 2; ++u) {
            const int s = 16 * u + lr;
            #pragma unroll
            for (int q = 0; q < 4; ++q) {
                const int o = 4 * g + q;
                if (o < 10)
                    res_s[s * 12 + o] += accb[u][q] + b4[4800 + o];
            }
        }
    }
    __syncthreads();

    for (int e = t; e < 320; e += 512)
        out[(size_t)row0 * 10 + e] = res_s[(e / 10) * 12 + (e % 10)];
}

// ---------------------------------------------------------------- launcher
extern "C" void kernel_launch(void* const* d_in, const int* in_sizes, int n_in,
                              void* d_out, int out_size, void* d_ws, size_t ws_size,
                              hipStream_t stream)
{
    const float* data = (const float*)d_in[0];
    const int*   midx = (const int*)d_in[1];
    const float* W1   = (const float*)d_in[2];
    const float* b1   = (const float*)d_in[3];
    const float* W2   = (const float*)d_in[4];
    const float* b2   = (const float*)d_in[5];
    const float* W3   = (const float*)d_in[6];
    const float* b3   = (const float*)d_in[7];
    const float* W4   = (const float*)d_in[8];
    const float* b4   = (const float*)d_in[9];
    float* out = (float*)d_out;

    f16* W1Th = (f16*)d_ws;                    // 262144 f16
    f16* W4h  = W1Th + (size_t)4096 * 64;      // 622592 f16
    f16* W2h  = W4h + (size_t)NPAD * 128;      // 16384 f16
    f16* W3h  = W2h + 256 * 64;                // 32768 f16

    k_prep<<<512, 256, 0, stream>>>(W1, W2, W3, W4, W1Th, W2h, W3h, W4h);
    k_main<<<512, 512, 0, stream>>>(data, midx, W1Th, b1, W2h, b2, W3h, b3,
                                    W4h, b4, out);
}

// Round 8
// 81.285 us; speedup vs baseline: 1.4338x; 1.4338x over previous
//
#include <hip/hip_runtime.h>

// INP=4096 MSK=64 HID=64 OUT=10  L1=64 L2=256 L3=128  B=16384  WVEC=4810
// k_prep : W1^T -> f16; W2/W3 -> f16; W4 -> f16 in MFMA FRAGMENT ORDER:
//          W4s[((c*4+kk)*4+mt)*64 + lane][8] = W4[64c+16mt+(lane&15)][32kk+8*(lane>>4)+j]
// k_main : per 64 samples (grid 256, 8 waves = 4 sample-groups x 2 chunk-parity):
//   issue pair-0 W4 stage + xm random-gather early -> l1 dedup-sum -> l2/l3 MFMA
//   -> double-buffered LDS-staged W4 GEMM (linear conflict-free ds_read_b128,
//   reg-staged copy 1 pair ahead) -> fused per-sample einsum epilogues.

typedef _Float16 f16;
typedef _Float16 f16x8 __attribute__((ext_vector_type(8)));
typedef _Float16 f16x4 __attribute__((ext_vector_type(4)));
typedef float    f32x4 __attribute__((ext_vector_type(4)));

#define NPAD 4864   // 4810 W4 rows padded to 76*64 (38 pairs of 64-row chunks)

// ---------------------------------------------------------------- prep
__global__ __launch_bounds__(256) void k_prep(
    const float* __restrict__ W1, const float* __restrict__ W2,
    const float* __restrict__ W3, const float* __restrict__ W4,
    f16* __restrict__ W1Th, f16* __restrict__ W2h,
    f16* __restrict__ W3h, f16* __restrict__ W4s)
{
    const int tid = blockIdx.x * 256 + threadIdx.x;
    const int stride = gridDim.x * 256;
    for (int e = tid; e < 4096 * 64; e += stride) {
        int j = e >> 6, i = e & 63;
        W1Th[e] = (f16)W1[(size_t)i * 4096 + j];
    }
    // fragment-ordered W4
    for (int e = tid; e < NPAD * 128; e += stride) {
        const int j    = e & 7;
        const int lane = (e >> 3) & 63;
        const int mt   = (e >> 9) & 3;
        const int kk   = (e >> 11) & 3;
        const int c    = e >> 13;
        const int lr = lane & 15, g = lane >> 4;
        const int row = 64 * c + 16 * mt + lr;
        const int col = 32 * kk + 8 * g + j;
        W4s[e] = (row < 4810) ? (f16)W4[(size_t)row * 128 + col] : (f16)0.f;
    }
    for (int e = tid; e < 256 * 64; e += stride)  W2h[e] = (f16)W2[e];
    for (int e = tid; e < 128 * 256; e += stride) W3h[e] = (f16)W3[e];
}

// ---------------------------------------------------------------- main
// LDS (120 KB, 1 block/CU):
//  uMain[64K]: front = h2[64][256]f16 swz (@0, 32K) + h1[64][64]f16 swz (@32768, 8K)
//              gemm  = W4 stage double-buffer (2 x 32K chunk-pairs)
//  uB[17K]   : idx[64][64]i32 -> xm[64][68]f32
//  uC[17K]   : h3[64][128]f16 swz -> hid[64][68]f32
//  b4_s 19.5K, res_s 3K
__global__ __launch_bounds__(512, 2) void k_main(
    const float* __restrict__ data, const int* __restrict__ midx,
    const f16* __restrict__ W1Th, const float* __restrict__ b1,
    const f16* __restrict__ W2h, const float* __restrict__ b2,
    const f16* __restrict__ W3h, const float* __restrict__ b3,
    const f16* __restrict__ W4s, const float* __restrict__ b4,
    float* __restrict__ out)
{
    __shared__ __align__(16) char uMain[65536];
    __shared__ __align__(16) char uB[17408];
    __shared__ __align__(16) char uC[17408];
    __shared__ __align__(16) float b4_s[NPAD];
    __shared__ __align__(16) float res_s[64 * 12];

    const int t = threadIdx.x, w = t >> 6, lane = t & 63;
    const int lr = lane & 15, g = lane >> 4;
    const int sg = w >> 1, cp = w & 1;      // sample-group 0..3, chunk parity 0..1
    const int row0 = blockIdx.x * 64;
    const f32x4 zero = {0.f, 0.f, 0.f, 0.f};

    int*   idx_s = (int*)uB;
    char*  h2b   = uMain;
    char*  h1b   = uMain + 32768;
    char*  h3b   = uC;
    char*  stage = uMain;
    float* xm_s  = (float*)uB;             // [64][68]
    float* hid_s = (float*)uC;             // [64][68]

    const char* W4b = (const char*)W4s;
    f32x4 rS0, rS1, rS2, rS3;              // staged 64B/thread (one 32KB pair)

    // ---- prologue: issue pair-0 W4 stage loads (land at ph6)
    {
        const char* gp = W4b + (size_t)t * 16;
        rS0 = *(const f32x4*)(gp);
        rS1 = *(const f32x4*)(gp + 8192);
        rS2 = *(const f32x4*)(gp + 16384);
        rS3 = *(const f32x4*)(gp + 24576);
    }

    // ---- phase 1: mask indices + b4 -> LDS
    for (int e = t; e < 4096; e += 512)
        idx_s[e] = midx[(size_t)row0 * 64 + e];
    for (int i = t; i < NPAD; i += 512)
        b4_s[i] = (i < 4810) ? b4[i] : 0.f;
    __syncthreads();

    // ---- phase 2: issue xm random gather (8 loads/thread, drain later)
    float xr[8];
    #pragma unroll
    for (int k = 0; k < 8; ++k) {
        const int e = k * 512 + t;           // e = s*64 + m
        xr[k] = data[(size_t)(row0 + (e >> 6)) * 4096 + idx_s[e]];
    }

    // ---- phase 3: layer 1 dedup gather-sum (wave w: samples 8w..8w+7)
    {
        const f32x4 b1v = *(const f32x4*)&b1[lr * 4];
        for (int p = 0; p < 4; ++p) {
            const int s0 = 8 * w + 2 * p, s1 = s0 + 1;
            f32x4 a0 = zero, a1 = zero;
            #pragma unroll
            for (int tt = 0; tt < 16; ++tt) {
                const int i = g * 16 + tt;
                const int c0 = idx_s[s0 * 64 + i];
                const int q0 = (i > 0) ? idx_s[s0 * 64 + i - 1] : -1;
                const int c1 = idx_s[s1 * 64 + i];
                const int q1 = (i > 0) ? idx_s[s1 * 64 + i - 1] : -1;
                const f16x4 w0 = *(const f16x4*)&W1Th[c0 * 64 + lr * 4];
                const f16x4 w1 = *(const f16x4*)&W1Th[c1 * 64 + lr * 4];
                #pragma unroll
                for (int q = 0; q < 4; ++q) {
                    a0[q] += (c0 != q0) ? (float)w0[q] : 0.f;
                    a1[q] += (c1 != q1) ? (float)w1[q] : 0.f;
                }
            }
            #pragma unroll
            for (int q = 0; q < 4; ++q) {
                a0[q] += __shfl_xor(a0[q], 16);
                a0[q] += __shfl_xor(a0[q], 32);
                a1[q] += __shfl_xor(a1[q], 16);
                a1[q] += __shfl_xor(a1[q], 32);
            }
            if (g == 0) {
                f16x4 h0, h1v;
                #pragma unroll
                for (int q = 0; q < 4; ++q) {
                    h0[q]  = (f16)fmaxf(a0[q] + b1v[q], 0.f);
                    h1v[q] = (f16)fmaxf(a1[q] + b1v[q], 0.f);
                }
                *(f16x4*)(h1b + ((s0 * 128 + lr * 8) ^ ((s0 & 7) << 4))) = h0;
                *(f16x4*)(h1b + ((s1 * 128 + lr * 8) ^ ((s1 & 7) << 4))) = h1v;
            }
        }
    }
    __syncthreads();

    // ---- phase 4: layer 2 (wave w owns n in [32w,32w+32), K=64)
    {
        f16x8 a2[2][2], bh[4][2];
        #pragma unroll
        for (int mt = 0; mt < 2; ++mt)
            #pragma unroll
            for (int kk = 0; kk < 2; ++kk)
                a2[mt][kk] = *(const f16x8*)&W2h[(32 * w + 16 * mt + lr) * 64 + 32 * kk + 8 * g];
        #pragma unroll
        for (int rt = 0; rt < 4; ++rt)
            #pragma unroll
            for (int kk = 0; kk < 2; ++kk) {
                const int s = 16 * rt + lr;
                bh[rt][kk] = *(const f16x8*)(h1b + ((s * 128 + (32 * kk + 8 * g) * 2) ^ ((s & 7) << 4)));
            }

        f32x4 acc2[2][4];
        #pragma unroll
        for (int mt = 0; mt < 2; ++mt)
            #pragma unroll
            for (int rt = 0; rt < 4; ++rt) {
                acc2[mt][rt] = __builtin_amdgcn_mfma_f32_16x16x32_f16(a2[mt][0], bh[rt][0], zero, 0, 0, 0);
                acc2[mt][rt] = __builtin_amdgcn_mfma_f32_16x16x32_f16(a2[mt][1], bh[rt][1], acc2[mt][rt], 0, 0, 0);
            }

        #pragma unroll
        for (int mt = 0; mt < 2; ++mt) {
            const f32x4 bv = *(const f32x4*)&b2[32 * w + 16 * mt + 4 * g];
            #pragma unroll
            for (int rt = 0; rt < 4; ++rt) {
                const int s = 16 * rt + lr;
                f16x4 hv;
                #pragma unroll
                for (int q = 0; q < 4; ++q)
                    hv[q] = (f16)fmaxf(acc2[mt][rt][q] + bv[q], 0.f);
                *(f16x4*)(h2b + ((s * 512 + (32 * w + 16 * mt + 4 * g) * 2) ^ ((s & 7) << 4))) = hv;
            }
        }
    }
    __syncthreads();

    // ---- phase 5: layer 3 (wave w owns n in [16w,16w+16), K=256)
    {
        f32x4 acc3[4] = {zero, zero, zero, zero};
        #pragma unroll 2
        for (int kk = 0; kk < 8; ++kk) {
            const f16x8 a3 = *(const f16x8*)&W3h[(16 * w + lr) * 256 + 32 * kk + 8 * g];
            #pragma unroll
            for (int rt = 0; rt < 4; ++rt) {
                const int s = 16 * rt + lr;
                const f16x8 bb = *(const f16x8*)(h2b + ((s * 512 + (32 * kk + 8 * g) * 2) ^ ((s & 7) << 4)));
                acc3[rt] = __builtin_amdgcn_mfma_f32_16x16x32_f16(a3, bb, acc3[rt], 0, 0, 0);
            }
        }
        const f32x4 bv3 = *(const f32x4*)&b3[16 * w + 4 * g];
        #pragma unroll
        for (int rt = 0; rt < 4; ++rt) {
            const int s = 16 * rt + lr;
            f16x4 hv;
            #pragma unroll
            for (int q = 0; q < 4; ++q)
                hv[q] = (f16)fmaxf(acc3[rt][q] + bv3[q], 0.f);
            *(f16x4*)(h3b + ((s * 256 + (16 * w + 4 * g) * 2) ^ ((s & 7) << 4))) = hv;
        }
    }
    __syncthreads();   // h3 ready; h1/h2/idx dead -> stage region free

    // ---- phase 6: commit pair 0 to LDS, issue pair 1; xm->LDS; bfrag
    {
        char* lp = stage + t * 16;           // pair 0 -> buf 0
        *(f32x4*)(lp)         = rS0;
        *(f32x4*)(lp + 8192)  = rS1;
        *(f32x4*)(lp + 16384) = rS2;
        *(f32x4*)(lp + 24576) = rS3;
    }
    {
        const char* gp = W4b + 32768 + (size_t)t * 16;   // issue pair 1
        rS0 = *(const f32x4*)(gp);
        rS1 = *(const f32x4*)(gp + 8192);
        rS2 = *(const f32x4*)(gp + 16384);
        rS3 = *(const f32x4*)(gp + 24576);
    }
    #pragma unroll
    for (int k = 0; k < 8; ++k) {
        const int e = k * 512 + t;
        xm_s[(e >> 6) * 68 + (e & 63)] = xr[k];
    }
    const int s = 16 * sg + lr;              // this wave's sample
    f16x8 bfrag[4];
    #pragma unroll
    for (int kk = 0; kk < 4; ++kk)
        bfrag[kk] = *(const f16x8*)(h3b + ((s * 256 + (32 * kk + 8 * g) * 2) ^ ((s & 7) << 4)));
    __syncthreads();

    f32x4 xmr[4];
    #pragma unroll
    for (int mt = 0; mt < 4; ++mt)
        xmr[mt] = *(const f32x4*)&xm_s[s * 68 + 16 * mt + 4 * g];
    f32x4 hidr[4];

    // ================= staged W4 GEMM: 38 chunk-pairs =================
    for (int tp = 0; tp < 38; ++tp) {
        const char* pb = stage + (tp & 1) * 32768;

        if (tp < 32) {                       // inp_w chunks 0..63
            const int c = 2 * tp + cp;
            const char* cb = pb + (c & 1) * 16384;
            f32x4 acc[4] = {zero, zero, zero, zero};
            #pragma unroll
            for (int kk = 0; kk < 4; ++kk) {
                f16x8 af[4];
                #pragma unroll
                for (int mt = 0; mt < 4; ++mt)
                    af[mt] = *(const f16x8*)(cb + kk * 4096 + mt * 1024 + lane * 16);
                #pragma unroll
                for (int mt = 0; mt < 4; ++mt)
                    acc[mt] = __builtin_amdgcn_mfma_f32_16x16x32_f16(af[mt], bfrag[kk], acc[mt], 0, 0, 0);
            }
            float sum = 0.f;
            #pragma unroll
            for (int mt = 0; mt < 4; ++mt) {
                const f32x4 bv = *(const f32x4*)&b4_s[64 * c + 16 * mt + 4 * g];
                #pragma unroll
                for (int q = 0; q < 4; ++q)
                    sum += (acc[mt][q] + bv[q]) * xmr[mt][q];
            }
            sum += __shfl_xor(sum, 16);
            sum += __shfl_xor(sum, 32);
            if (g == 0) hid_s[s * 68 + c] = sum;
        } else if (tp == 32) {               // chunk 64 = inp_b (+ReLU), then 65
            f32x4 accb[2] = {zero, zero};
            #pragma unroll
            for (int kk = 0; kk < 4; ++kk) {
                f16x8 af[2];
                #pragma unroll
                for (int i = 0; i < 2; ++i)
                    af[i] = *(const f16x8*)(pb + kk * 4096 + (2 * cp + i) * 1024 + lane * 16);
                #pragma unroll
                for (int i = 0; i < 2; ++i)
                    accb[i] = __builtin_amdgcn_mfma_f32_16x16x32_f16(af[i], bfrag[kk], accb[i], 0, 0, 0);
            }
            #pragma unroll
            for (int i = 0; i < 2; ++i) {
                const int hb = 16 * (2 * cp + i) + 4 * g;
                f32x4 hv = *(const f32x4*)&hid_s[s * 68 + hb];
                const f32x4 bv = *(const f32x4*)&b4_s[4096 + hb];
                #pragma unroll
                for (int q = 0; q < 4; ++q)
                    hv[q] = fmaxf(hv[q] + accb[i][q] + bv[q], 0.f);
                *(f32x4*)&hid_s[s * 68 + hb] = hv;
            }
            __syncthreads();                 // hid complete
            #pragma unroll
            for (int mt = 0; mt < 4; ++mt)
                hidr[mt] = *(const f32x4*)&hid_s[s * 68 + 16 * mt + 4 * g];
            if (cp == 0) {                   // chunk 65 = first out_w
                const char* cb = pb + 16384;
                f32x4 acc[4] = {zero, zero, zero, zero};
                #pragma unroll
                for (int kk = 0; kk < 4; ++kk) {
                    f16x8 af[4];
                    #pragma unroll
                    for (int mt = 0; mt < 4; ++mt)
                        af[mt] = *(const f16x8*)(cb + kk * 4096 + mt * 1024 + lane * 16);
                    #pragma unroll
                    for (int mt = 0; mt < 4; ++mt)
                        acc[mt] = __builtin_amdgcn_mfma_f32_16x16x32_f16(af[mt], bfrag[kk], acc[mt], 0, 0, 0);
                }
                float sum = 0.f;
                #pragma unroll
                for (int mt = 0; mt < 4; ++mt) {
                    const f32x4 bv = *(const f32x4*)&b4_s[4160 + 16 * mt + 4 * g];
                    #pragma unroll
                    for (int q = 0; q < 4; ++q)
                        sum += (acc[mt][q] + bv[q]) * hidr[mt][q];
                }
                sum += __shfl_xor(sum, 16);
                sum += __shfl_xor(sum, 32);
                if (g == 0) res_s[s * 12 + 0] = sum;
            }
        } else {                             // chunks 66..74 (75 post-loop)
            const int c = 2 * tp + cp;
            if (c < 75) {
                const char* cb = pb + (c & 1) * 16384;
                f32x4 acc[4] = {zero, zero, zero, zero};
                #pragma unroll
                for (int kk = 0; kk < 4; ++kk) {
                    f16x8 af[4];
                    #pragma unroll
                    for (int mt = 0; mt < 4; ++mt)
                        af[mt] = *(const f16x8*)(cb + kk * 4096 + mt * 1024 + lane * 16);
                    #pragma unroll
                    for (int mt = 0; mt < 4; ++mt)
                        acc[mt] = __builtin_amdgcn_mfma_f32_16x16x32_f16(af[mt], bfrag[kk], acc[mt], 0, 0, 0);
                }
                float sum = 0.f;
                #pragma unroll
                for (int mt = 0; mt < 4; ++mt) {
                    const f32x4 bv = *(const f32x4*)&b4_s[64 * c + 16 * mt + 4 * g];
                    #pragma unroll
                    for (int q = 0; q < 4; ++q)
                        sum += (acc[mt][q] + bv[q]) * hidr[mt][q];
                }
                sum += __shfl_xor(sum, 16);
                sum += __shfl_xor(sum, 32);
                if (g == 0) res_s[s * 12 + (c - 65)] = sum;
            }
        }
        __syncthreads();                     // pair tp fully consumed

        if (tp + 1 < 38) {                   // commit pair tp+1, issue tp+2
            char* lp = stage + ((tp + 1) & 1) * 32768 + t * 16;
            *(f32x4*)(lp)         = rS0;
            *(f32x4*)(lp + 8192)  = rS1;
            *(f32x4*)(lp + 16384) = rS2;
            *(f32x4*)(lp + 24576) = rS3;
            if (tp + 2 < 38) {
                const char* gp = W4b + (size_t)(tp + 2) * 32768 + (size_t)t * 16;
                rS0 = *(const f32x4*)(gp);
                rS1 = *(const f32x4*)(gp + 8192);
                rS2 = *(const f32x4*)(gp + 16384);
                rS3 = *(const f32x4*)(gp + 24576);
            }
            __syncthreads();                 // pair tp+1 ready
        }
    }

    // ---- chunk 75 = out_b (rows 4800..4809; pair 37 still in buf[1])
    if (cp == 1) {
        const char* cb = stage + 32768 + 16384;
        f32x4 acc = zero;
        #pragma unroll
        for (int kk = 0; kk < 4; ++kk) {
            const f16x8 af = *(const f16x8*)(cb + kk * 4096 + lane * 16);
            acc = __builtin_amdgcn_mfma_f32_16x16x32_f16(af, bfrag[kk], acc, 0, 0, 0);
        }
        #pragma unroll
        for (int q = 0; q < 4; ++q) {
            const int o = 4 * g + q;
            if (o < 10)
                res_s[s * 12 + o] += acc[q] + b4_s[4800 + o];
        }
    }
    __syncthreads();

    for (int e = t; e < 640; e += 512)
        out[(size_t)row0 * 10 + e] = res_s[(e / 10) * 12 + (e % 10)];
}

// ---------------------------------------------------------------- launcher
extern "C" void kernel_launch(void* const* d_in, const int* in_sizes, int n_in,
                              void* d_out, int out_size, void* d_ws, size_t ws_size,
                              hipStream_t stream)
{
    const float* data = (const float*)d_in[0];
    const int*   midx = (const int*)d_in[1];
    const float* W1   = (const float*)d_in[2];
    const float* b1   = (const float*)d_in[3];
    const float* W2   = (const float*)d_in[4];
    const float* b2   = (const float*)d_in[5];
    const float* W3   = (const float*)d_in[6];
    const float* b3   = (const float*)d_in[7];
    const float* W4   = (const float*)d_in[8];
    const float* b4   = (const float*)d_in[9];
    float* out = (float*)d_out;

    f16* W1Th = (f16*)d_ws;                    // 262144 f16
    f16* W4s  = W1Th + (size_t)4096 * 64;      // 622592 f16 (fragment-ordered)
    f16* W2h  = W4s + (size_t)NPAD * 128;      // 16384 f16
    f16* W3h  = W2h + 256 * 64;                // 32768 f16

    k_prep<<<512, 256, 0, stream>>>(W1, W2, W3, W4, W1Th, W2h, W3h, W4s);
    k_main<<<256, 512, 0, stream>>>(data, midx, W1Th, b1, W2h, b2, W3h, b3,
                                    W4s, b4, out);
}

// Round 9
// 78.464 us; speedup vs baseline: 1.4853x; 1.0360x over previous
//
#include <hip/hip_runtime.h>

// INP=4096 MSK=64 HID=64 OUT=10  L1=64 L2=256 L3=128  B=16384  WVEC=4810
// k_prep : W1^T -> f16; W2/W3 -> f16; W4 -> f16 in MFMA FRAGMENT ORDER:
//          W4s[(((c*4+kk)*4+mt)*64+lane)*8+j] = W4[64c+16mt+(lane&15)][32kk+8*(lane>>4)+j]
// k_main : per 64 samples (grid 256, 8 waves):
//   front: xm random-gather issue -> L1 dedup-sum -> L2/L3 MFMA (swizzled LDS)
//   GEMM : NO LDS staging. Each wave holds bfrag for ALL 64 samples (4 u-sets)
//          + packed-f16 xm/hid registers; A-fragments stream from L2 once per
//          block (16 coalesced dwordx4 per chunk -> 64 MFMA, kk ping-pong +
//          next-chunk prefetch). 6 barriers total in GEMM phase.

typedef _Float16 f16;
typedef _Float16 f16x8 __attribute__((ext_vector_type(8)));
typedef _Float16 f16x4 __attribute__((ext_vector_type(4)));
typedef float    f32x4 __attribute__((ext_vector_type(4)));

#define NPAD 4864   // 4810 W4 rows padded to 76*64

// ---------------------------------------------------------------- prep
__global__ __launch_bounds__(256) void k_prep(
    const float* __restrict__ W1, const float* __restrict__ W2,
    const float* __restrict__ W3, const float* __restrict__ W4,
    f16* __restrict__ W1Th, f16* __restrict__ W2h,
    f16* __restrict__ W3h, f16* __restrict__ W4s)
{
    const int tid = blockIdx.x * 256 + threadIdx.x;
    const int stride = gridDim.x * 256;
    for (int e = tid; e < 4096 * 64; e += stride) {
        int j = e >> 6, i = e & 63;
        W1Th[e] = (f16)W1[(size_t)i * 4096 + j];
    }
    // fragment-ordered W4
    for (int e = tid; e < NPAD * 128; e += stride) {
        const int j    = e & 7;
        const int lane = (e >> 3) & 63;
        const int mt   = (e >> 9) & 3;
        const int kk   = (e >> 11) & 3;
        const int c    = e >> 13;
        const int lr = lane & 15, g = lane >> 4;
        const int row = 64 * c + 16 * mt + lr;
        const int col = 32 * kk + 8 * g + j;
        W4s[e] = (row < 4810) ? (f16)W4[(size_t)row * 128 + col] : (f16)0.f;
    }
    for (int e = tid; e < 256 * 64; e += stride)  W2h[e] = (f16)W2[e];
    for (int e = tid; e < 128 * 256; e += stride) W3h[e] = (f16)W3[e];
}

// ---------------------------------------------------------------- main
// LDS (77 KB):
//  uMain[40K]: h2[64][256]f16 swz (@0) + h1[64][64]f16 swz (@32768)   [front only]
//  uB[17K]   : idx[64][64]i32 -> xm[64][68]f32 (transient)
//  uC[17K]   : h3[64][128]f16 swz -> hid[64][68]f32
//  res_s 3K
__global__ __launch_bounds__(512, 2) void k_main(
    const float* __restrict__ data, const int* __restrict__ midx,
    const f16* __restrict__ W1Th, const float* __restrict__ b1,
    const f16* __restrict__ W2h, const float* __restrict__ b2,
    const f16* __restrict__ W3h, const float* __restrict__ b3,
    const f16* __restrict__ W4s, const float* __restrict__ b4,
    float* __restrict__ out)
{
    __shared__ __align__(16) char uMain[40960];
    __shared__ __align__(16) char uB[17408];
    __shared__ __align__(16) char uC[17408];
    __shared__ __align__(16) float res_s[64 * 12];

    const int t = threadIdx.x, w = t >> 6, lane = t & 63;
    const int lr = lane & 15, g = lane >> 4;
    const int row0 = blockIdx.x * 64;
    const f32x4 zero = {0.f, 0.f, 0.f, 0.f};

    int*   idx_s = (int*)uB;
    char*  h2b   = uMain;
    char*  h1b   = uMain + 32768;
    char*  h3b   = uC;
    float* xm_s  = (float*)uB;             // [64][68]
    float* hid_s = (float*)uC;             // [64][68]

    // ---- phase 1: mask indices -> LDS
    for (int e = t; e < 4096; e += 512)
        idx_s[e] = midx[(size_t)row0 * 64 + e];
    __syncthreads();

    // ---- phase 2: issue xm random gather (8 loads/thread, drain later)
    float xr[8];
    #pragma unroll
    for (int k = 0; k < 8; ++k) {
        const int e = k * 512 + t;           // e = s*64 + m
        xr[k] = data[(size_t)(row0 + (e >> 6)) * 4096 + idx_s[e]];
    }

    // ---- phase 3: layer 1 dedup gather-sum (wave w: samples 8w..8w+7)
    {
        const f32x4 b1v = *(const f32x4*)&b1[lr * 4];
        for (int p = 0; p < 4; ++p) {
            const int s0 = 8 * w + 2 * p, s1 = s0 + 1;
            f32x4 a0 = zero, a1 = zero;
            #pragma unroll
            for (int tt = 0; tt < 16; ++tt) {
                const int i = g * 16 + tt;
                const int c0 = idx_s[s0 * 64 + i];
                const int q0 = (i > 0) ? idx_s[s0 * 64 + i - 1] : -1;
                const int c1 = idx_s[s1 * 64 + i];
                const int q1 = (i > 0) ? idx_s[s1 * 64 + i - 1] : -1;
                const f16x4 w0 = *(const f16x4*)&W1Th[c0 * 64 + lr * 4];
                const f16x4 w1 = *(const f16x4*)&W1Th[c1 * 64 + lr * 4];
                #pragma unroll
                for (int q = 0; q < 4; ++q) {
                    a0[q] += (c0 != q0) ? (float)w0[q] : 0.f;
                    a1[q] += (c1 != q1) ? (float)w1[q] : 0.f;
                }
            }
            #pragma unroll
            for (int q = 0; q < 4; ++q) {
                a0[q] += __shfl_xor(a0[q], 16);
                a0[q] += __shfl_xor(a0[q], 32);
                a1[q] += __shfl_xor(a1[q], 16);
                a1[q] += __shfl_xor(a1[q], 32);
            }
            if (g == 0) {
                f16x4 h0, h1v;
                #pragma unroll
                for (int q = 0; q < 4; ++q) {
                    h0[q]  = (f16)fmaxf(a0[q] + b1v[q], 0.f);
                    h1v[q] = (f16)fmaxf(a1[q] + b1v[q], 0.f);
                }
                *(f16x4*)(h1b + ((s0 * 128 + lr * 8) ^ ((s0 & 7) << 4))) = h0;
                *(f16x4*)(h1b + ((s1 * 128 + lr * 8) ^ ((s1 & 7) << 4))) = h1v;
            }
        }
    }
    __syncthreads();

    // ---- phase 4: layer 2 (wave w owns n in [32w,32w+32), K=64)
    {
        f16x8 a2[2][2], bh[4][2];
        #pragma unroll
        for (int mt = 0; mt < 2; ++mt)
            #pragma unroll
            for (int kk = 0; kk < 2; ++kk)
                a2[mt][kk] = *(const f16x8*)&W2h[(32 * w + 16 * mt + lr) * 64 + 32 * kk + 8 * g];
        #pragma unroll
        for (int rt = 0; rt < 4; ++rt)
            #pragma unroll
            for (int kk = 0; kk < 2; ++kk) {
                const int s = 16 * rt + lr;
                bh[rt][kk] = *(const f16x8*)(h1b + ((s * 128 + (32 * kk + 8 * g) * 2) ^ ((s & 7) << 4)));
            }

        f32x4 acc2[2][4];
        #pragma unroll
        for (int mt = 0; mt < 2; ++mt)
            #pragma unroll
            for (int rt = 0; rt < 4; ++rt) {
                acc2[mt][rt] = __builtin_amdgcn_mfma_f32_16x16x32_f16(a2[mt][0], bh[rt][0], zero, 0, 0, 0);
                acc2[mt][rt] = __builtin_amdgcn_mfma_f32_16x16x32_f16(a2[mt][1], bh[rt][1], acc2[mt][rt], 0, 0, 0);
            }

        #pragma unroll
        for (int mt = 0; mt < 2; ++mt) {
            const f32x4 bv = *(const f32x4*)&b2[32 * w + 16 * mt + 4 * g];
            #pragma unroll
            for (int rt = 0; rt < 4; ++rt) {
                const int s = 16 * rt + lr;
                f16x4 hv;
                #pragma unroll
                for (int q = 0; q < 4; ++q)
                    hv[q] = (f16)fmaxf(acc2[mt][rt][q] + bv[q], 0.f);
                *(f16x4*)(h2b + ((s * 512 + (32 * w + 16 * mt + 4 * g) * 2) ^ ((s & 7) << 4))) = hv;
            }
        }
    }
    __syncthreads();

    // ---- phase 5: layer 3 (wave w owns n in [16w,16w+16), K=256)
    {
        f32x4 acc3[4] = {zero, zero, zero, zero};
        #pragma unroll 2
        for (int kk = 0; kk < 8; ++kk) {
            const f16x8 a3 = *(const f16x8*)&W3h[(16 * w + lr) * 256 + 32 * kk + 8 * g];
            #pragma unroll
            for (int rt = 0; rt < 4; ++rt) {
                const int s = 16 * rt + lr;
                const f16x8 bb = *(const f16x8*)(h2b + ((s * 512 + (32 * kk + 8 * g) * 2) ^ ((s & 7) << 4)));
                acc3[rt] = __builtin_amdgcn_mfma_f32_16x16x32_f16(a3, bb, acc3[rt], 0, 0, 0);
            }
        }
        const f32x4 bv3 = *(const f32x4*)&b3[16 * w + 4 * g];
        #pragma unroll
        for (int rt = 0; rt < 4; ++rt) {
            const int s = 16 * rt + lr;
            f16x4 hv;
            #pragma unroll
            for (int q = 0; q < 4; ++q)
                hv[q] = (f16)fmaxf(acc3[rt][q] + bv3[q], 0.f);
            *(f16x4*)(h3b + ((s * 256 + (16 * w + 4 * g) * 2) ^ ((s & 7) << 4))) = hv;
        }
    }
    __syncthreads();   // h3 ready; h1/h2/idx dead

    // ---- phase 6: xm -> LDS; bfrag for ALL 64 samples (4 u-sets)
    #pragma unroll
    for (int k = 0; k < 8; ++k) {
        const int e = k * 512 + t;
        xm_s[(e >> 6) * 68 + (e & 63)] = xr[k];
    }
    f16x8 bfrag[4][4];                     // [kk][u]
    #pragma unroll
    for (int u = 0; u < 4; ++u)
        #pragma unroll
        for (int kk = 0; kk < 4; ++kk) {
            const int s = 16 * u + lr;
            bfrag[kk][u] = *(const f16x8*)(h3b + ((s * 256 + (32 * kk + 8 * g) * 2) ^ ((s & 7) << 4)));
        }
    __syncthreads();   // xm_s complete; h3 reads complete (hid aliases uC)

    // xm packed f16 registers: xmr[mt][u] covers xm[16u+lr][16mt+4g..+4]
    f16x4 xmr[4][4];
    #pragma unroll
    for (int mt = 0; mt < 4; ++mt)
        #pragma unroll
        for (int u = 0; u < 4; ++u) {
            const f32x4 xv = *(const f32x4*)&xm_s[(16 * u + lr) * 68 + 16 * mt + 4 * g];
            f16x4 xh;
            #pragma unroll
            for (int q = 0; q < 4; ++q) xh[q] = (f16)xv[q];
            xmr[mt][u] = xh;
        }

    const char* W4b = (const char*)W4s;
    const int afoff = lane * 16;

#define LDAF(dst, c, kk) { const char* cb_ = W4b + (size_t)(c) * 16384 + (kk) * 4096 + afoff; \
    dst[0] = *(const f16x8*)(cb_);        dst[1] = *(const f16x8*)(cb_ + 1024); \
    dst[2] = *(const f16x8*)(cb_ + 2048); dst[3] = *(const f16x8*)(cb_ + 3072); }

#define MFMA16(af, kk) { \
    _Pragma("unroll") for (int mt = 0; mt < 4; ++mt) \
    _Pragma("unroll") for (int u = 0; u < 4; ++u) \
        acc[mt][u] = __builtin_amdgcn_mfma_f32_16x16x32_f16(af[mt], bfrag[kk][u], acc[mt][u], 0, 0, 0); }

    // ---- inp_w chunks: wave w -> c = w, w+8, ..., w+56
    {
        f16x8 afA[4], afB[4];
        LDAF(afA, w, 0)
        for (int i = 0; i < 8; ++i) {
            const int c = 8 * i + w;
            f32x4 bv[4];
            #pragma unroll
            for (int mt = 0; mt < 4; ++mt)
                bv[mt] = *(const f32x4*)&b4[64 * c + 16 * mt + 4 * g];
            LDAF(afB, c, 1)
            f32x4 acc[4][4];
            #pragma unroll
            for (int mt = 0; mt < 4; ++mt)
                #pragma unroll
                for (int u = 0; u < 4; ++u)
                    acc[mt][u] = __builtin_amdgcn_mfma_f32_16x16x32_f16(afA[mt], bfrag[0][u], zero, 0, 0, 0);
            LDAF(afA, c, 2)
            MFMA16(afB, 1)
            LDAF(afB, c, 3)
            MFMA16(afA, 2)
            if (i < 7) { LDAF(afA, 8 * (i + 1) + w, 0) }
            MFMA16(afB, 3)

            #pragma unroll
            for (int u = 0; u < 4; ++u) {
                float sum = 0.f;
                #pragma unroll
                for (int mt = 0; mt < 4; ++mt)
                    #pragma unroll
                    for (int q = 0; q < 4; ++q)
                        sum += (acc[mt][u][q] + bv[mt][q]) * (float)xmr[mt][u][q];
                sum += __shfl_xor(sum, 16);
                sum += __shfl_xor(sum, 32);
                if (g == 0) hid_s[(16 * u + lr) * 68 + c] = sum;
            }
        }
    }

    // ---- chunk 64 (inp_b): waves 0..3 handle mt=w; compute before barrier
    f32x4 acc64[4] = {zero, zero, zero, zero};
    if (w < 4) {
        f16x8 af64[4];
        #pragma unroll
        for (int kk = 0; kk < 4; ++kk)
            af64[kk] = *(const f16x8*)(W4b + (size_t)64 * 16384 + kk * 4096 + w * 1024 + afoff);
        #pragma unroll
        for (int kk = 0; kk < 4; ++kk)
            #pragma unroll
            for (int u = 0; u < 4; ++u)
                acc64[u] = __builtin_amdgcn_mfma_f32_16x16x32_f16(af64[kk], bfrag[kk][u], acc64[u], 0, 0, 0);
    }
    __syncthreads();                       // all inp hid writes done
    if (w < 4) {
        const f32x4 bv64 = *(const f32x4*)&b4[4096 + 16 * w + 4 * g];
        #pragma unroll
        for (int u = 0; u < 4; ++u) {
            float* hp = &hid_s[(16 * u + lr) * 68 + 16 * w + 4 * g];
            f32x4 hv = *(const f32x4*)hp;
            #pragma unroll
            for (int q = 0; q < 4; ++q)
                hv[q] = hv[q] + acc64[u][q] + bv64[q];
            *(f32x4*)hp = hv;
        }
    }
    __syncthreads();
    // ReLU hid
    for (int e = t; e < 4096; e += 512) {
        const int si = e >> 6, h = e & 63;
        hid_s[si * 68 + h] = fmaxf(hid_s[si * 68 + h], 0.f);
    }
    __syncthreads();
    // hid packed f16 registers (reuse xmr storage)
    #pragma unroll
    for (int mt = 0; mt < 4; ++mt)
        #pragma unroll
        for (int u = 0; u < 4; ++u) {
            const f32x4 hv = *(const f32x4*)&hid_s[(16 * u + lr) * 68 + 16 * mt + 4 * g];
            f16x4 xh;
            #pragma unroll
            for (int q = 0; q < 4; ++q) xh[q] = (f16)hv[q];
            xmr[mt][u] = xh;
        }

    // ---- out_w chunks 65..74: wave w -> 65+w; waves 6,7 also 73,74
    auto do_out = [&](int c) {
        f32x4 bv[4];
        #pragma unroll
        for (int mt = 0; mt < 4; ++mt)
            bv[mt] = *(const f32x4*)&b4[64 * c + 16 * mt + 4 * g];
        f16x8 afA[4], afB[4];
        LDAF(afA, c, 0)
        LDAF(afB, c, 1)
        f32x4 acc[4][4];
        #pragma unroll
        for (int mt = 0; mt < 4; ++mt)
            #pragma unroll
            for (int u = 0; u < 4; ++u)
                acc[mt][u] = __builtin_amdgcn_mfma_f32_16x16x32_f16(afA[mt], bfrag[0][u], zero, 0, 0, 0);
        LDAF(afA, c, 2)
        MFMA16(afB, 1)
        LDAF(afB, c, 3)
        MFMA16(afA, 2)
        MFMA16(afB, 3)
        #pragma unroll
        for (int u = 0; u < 4; ++u) {
            float sum = 0.f;
            #pragma unroll
            for (int mt = 0; mt < 4; ++mt)
                #pragma unroll
                for (int q = 0; q < 4; ++q)
                    sum += (acc[mt][u][q] + bv[mt][q]) * (float)xmr[mt][u][q];
            sum += __shfl_xor(sum, 16);
            sum += __shfl_xor(sum, 32);
            if (g == 0) res_s[(16 * u + lr) * 12 + (c - 65)] = sum;
        }
    };
    do_out(65 + w);
    if (w >= 6) do_out(67 + w);            // 73, 74

    // ---- chunk 75 (out_b rows 4800..4809): wave 4 computes (mt=0 only)
    f32x4 acc75[4] = {zero, zero, zero, zero};
    if (w == 4) {
        f16x8 af75[4];
        #pragma unroll
        for (int kk = 0; kk < 4; ++kk)
            af75[kk] = *(const f16x8*)(W4b + (size_t)75 * 16384 + kk * 4096 + afoff);
        #pragma unroll
        for (int kk = 0; kk < 4; ++kk)
            #pragma unroll
            for (int u = 0; u < 4; ++u)
                acc75[u] = __builtin_amdgcn_mfma_f32_16x16x32_f16(af75[kk], bfrag[kk][u], acc75[u], 0, 0, 0);
    }
    __syncthreads();                       // all out_w res writes done
    if (w == 4) {
        #pragma unroll
        for (int u = 0; u < 4; ++u)
            #pragma unroll
            for (int q = 0; q < 4; ++q) {
                const int o = 4 * g + q;
                if (o < 10)
                    res_s[(16 * u + lr) * 12 + o] += acc75[u][q] + b4[4800 + o];
            }
    }
    __syncthreads();

    for (int e = t; e < 640; e += 512)
        out[(size_t)row0 * 10 + e] = res_s[(e / 10) * 12 + (e % 10)];
#undef LDAF
#undef MFMA16
}

// ---------------------------------------------------------------- launcher
extern "C" void kernel_launch(void* const* d_in, const int* in_sizes, int n_in,
                              void* d_out, int out_size, void* d_ws, size_t ws_size,
                              hipStream_t stream)
{
    const float* data = (const float*)d_in[0];
    const int*   midx = (const int*)d_in[1];
    const float* W1   = (const float*)d_in[2];
    const float* b1   = (const float*)d_in[3];
    const float* W2   = (const float*)d_in[4];
    const float* b2   = (const float*)d_in[5];
    const float* W3   = (const float*)d_in[6];
    const float* b3   = (const float*)d_in[7];
    const float* W4   = (const float*)d_in[8];
    const float* b4   = (const float*)d_in[9];
    float* out = (float*)d_out;

    f16* W1Th = (f16*)d_ws;                    // 262144 f16
    f16* W4s  = W1Th + (size_t)4096 * 64;      // 622592 f16 (fragment-ordered)
    f16* W2h  = W4s + (size_t)NPAD * 128;      // 16384 f16
    f16* W3h  = W2h + 256 * 64;                // 32768 f16

    k_prep<<<512, 256, 0, stream>>>(W1, W2, W3, W4, W1Th, W2h, W3h, W4s);
    k_main<<<256, 512, 0, stream>>>(data, midx, W1Th, b1, W2h, b2, W3h, b3,
                                    W4s, b4, out);
}